// Round 1
// baseline (62.134 us; speedup 1.0000x reference)
//
#include <hip/hip_runtime.h>
#include <hip/hip_bf16.h>
#include <math.h>

#define HH 384
#define HWD 378          // 384 - 2*3
#define NSEG 48          // ceil(378/8)
#define NIMG 32
#define ROWSEGS (HWD * NSEG)       // 18144
#define NSIDS (NIMG * ROWSEGS)     // 580608
#define NB 512                     // main-kernel blocks

// Main kernel: each thread processes 8-column segments; accumulates
// S1(u,v) = sum d, S2(u,v) = sum d^2 for all 36 offsets in registers.
__global__ __launch_bounds__(256, 2) void probav_main_kernel(
    const float* __restrict__ predict,
    const float* __restrict__ target,
    const float* __restrict__ mask,
    double* __restrict__ partials /* [NB][72] */) {

  float s1[36], s2[36];
#pragma unroll
  for (int o = 0; o < 36; ++o) { s1[o] = 0.f; s2[o] = 0.f; }

  const int tid = blockIdx.x * 256 + threadIdx.x;
  const int tot = gridDim.x * 256;

  for (int sid = tid; sid < NSIDS; sid += tot) {
    const int img = sid / ROWSEGS;
    const int rem = sid - img * ROWSEGS;
    const int r   = rem / NSEG;          // output row 0..377
    const int sg  = rem - r * NSEG;
    const int jb  = sg * 8;              // output col base, 32B-aligned

    const int imgOff = img * (HH * HH);

    // ct[x] = target*mask at (r+3, jb+3+x); valid mask for jb+x < 378
    const float* tr = target + imgOff + (r + 3) * HH + (jb + 3);
    const float* mr = mask   + imgOff + (r + 3) * HH + (jb + 3);
    float ct[8], vm[8];
#pragma unroll
    for (int x = 0; x < 8; ++x) {
      ct[x] = tr[x] * mr[x];
      vm[x] = (jb + x < HWD) ? 1.0f : 0.0f;
    }

#pragma unroll
    for (int u = 0; u < 6; ++u) {
      const float4* pr = reinterpret_cast<const float4*>(predict + imgOff + (r + u) * HH + jb);
      const float4* mk = reinterpret_cast<const float4*>(mask    + imgOff + (r + u) * HH + jb);
      float pm[16];
#pragma unroll
      for (int q = 0; q < 4; ++q) {
        float4 a = pr[q];
        float4 b = mk[q];
        pm[4 * q + 0] = a.x * b.x;
        pm[4 * q + 1] = a.y * b.y;
        pm[4 * q + 2] = a.z * b.z;
        pm[4 * q + 3] = a.w * b.w;
      }
#pragma unroll
      for (int v = 0; v < 6; ++v) {
#pragma unroll
        for (int x = 0; x < 8; ++x) {
          float d = (ct[x] - pm[v + x]) * vm[x];
          s1[u * 6 + v] += d;
          s2[u * 6 + v] = fmaf(d, d, s2[u * 6 + v]);
        }
      }
    }
  }

  // Block reduction: 72 floats -> per-block double partials (no atomics).
  __shared__ double red[4][72];
  const int lane = threadIdx.x & 63;
  const int wid  = threadIdx.x >> 6;

#pragma unroll
  for (int o = 0; o < 36; ++o) {
    float a = s1[o];
    float b = s2[o];
#pragma unroll
    for (int off = 32; off > 0; off >>= 1) {
      a += __shfl_down(a, off);
      b += __shfl_down(b, off);
    }
    if (lane == 0) { red[wid][o] = (double)a; red[wid][36 + o] = (double)b; }
  }
  __syncthreads();
  if (threadIdx.x < 72) {
    double v = red[0][threadIdx.x] + red[1][threadIdx.x] +
               red[2][threadIdx.x] + red[3][threadIdx.x];
    partials[blockIdx.x * 72 + threadIdx.x] = v;
  }
}

// Final kernel: sum partials, compute 36 losses, min, score.
__global__ void probav_final_kernel(const double* __restrict__ partials,
                                    float* __restrict__ out) {
  __shared__ double S[72];
  const int t = threadIdx.x;
  if (t < 72) {
    double v = 0.0;
    for (int b = 0; b < NB; ++b) v += partials[b * 72 + t];
    S[t] = v;
  }
  __syncthreads();
  if (t == 0) {
    const double N = (double)NIMG * (double)HWD * (double)HWD;
    double best = 1e300;
#pragma unroll
    for (int o = 0; o < 36; ++o) {
      double m1 = S[o] / N;
      double m2 = S[36 + o] / N;
      double loss = m2 - m1 * m1;
      best = fmin(best, loss);
    }
    out[0] = (float)(-10.0 * log10(best));
  }
}

extern "C" void kernel_launch(void* const* d_in, const int* in_sizes, int n_in,
                              void* d_out, int out_size, void* d_ws, size_t ws_size,
                              hipStream_t stream) {
  const float* predict = (const float*)d_in[0];
  const float* target  = (const float*)d_in[1];
  const float* mask    = (const float*)d_in[2];
  float* out = (float*)d_out;
  double* partials = (double*)d_ws;   // NB*72*8 = 294912 bytes

  probav_main_kernel<<<NB, 256, 0, stream>>>(predict, target, mask, partials);
  probav_final_kernel<<<1, 128, 0, stream>>>(partials, out);
}